// Round 2
// baseline (215.436 us; speedup 1.0000x reference)
//
#include <hip/hip_runtime.h>

// B=32, T=1024, D=U=1024. The reference's softmax is over a SINGLETON axis,
// so attention_weights == 1.0 exactly, coverage[b,t] == t exactly, and
// context_vector == sum_t values[b,t,:]. All GEMM/tanh/scan work is dead code.
#define BB 32
#define TT 1024
#define DD 1024
#define DD4 (DD / 4)
#define TCHUNKS 64
#define TSUB (TT / TCHUNKS)  // 16 timesteps per chunk

// Phase 1: partial column sums. Grid (TCHUNKS, BB) = 2048 blocks (8/CU,
// 32 waves/CU = max occupancy), 256 threads. Thread owns one float4 column.
// Wave reads 64 x 16 B = 1 KB contiguous per iteration; 16 independent loads.
__global__ __launch_bounds__(256) void sum_partial_kernel(
    const float* __restrict__ values, float* __restrict__ partial) {
  const int chunk = blockIdx.x;
  const int b = blockIdx.y;
  const int d4 = threadIdx.x;
  const float4* vp = reinterpret_cast<const float4*>(values) +
                     ((size_t)b * TT + (size_t)chunk * TSUB) * DD4 + d4;
  float4 acc = make_float4(0.f, 0.f, 0.f, 0.f);
#pragma unroll
  for (int t = 0; t < TSUB; ++t) {
    float4 v = vp[(size_t)t * DD4];
    acc.x += v.x;
    acc.y += v.y;
    acc.z += v.z;
    acc.w += v.w;
  }
  reinterpret_cast<float4*>(partial)[((size_t)chunk * BB + b) * DD4 + d4] = acc;
}

// Phase 2: reduce TCHUNKS partials -> ctx [BB,DD], and fill aw=1.0 /
// cov[b,t]=t (32768 floats each = 4 per thread, float4 stores).
__global__ __launch_bounds__(256) void final_kernel(
    const float* __restrict__ partial, float* __restrict__ ctx,
    float* __restrict__ aw, float* __restrict__ cov) {
  const int idx = blockIdx.x * 256 + threadIdx.x;  // 0 .. BB*DD/4-1 (8192)
  const float4* pp = reinterpret_cast<const float4*>(partial);
  float4 acc = make_float4(0.f, 0.f, 0.f, 0.f);
#pragma unroll
  for (int c = 0; c < TCHUNKS; ++c) {
    float4 v = pp[(size_t)c * (BB * DD4) + idx];
    acc.x += v.x;
    acc.y += v.y;
    acc.z += v.z;
    acc.w += v.w;
  }
  reinterpret_cast<float4*>(ctx)[idx] = acc;

  reinterpret_cast<float4*>(aw)[idx] = make_float4(1.f, 1.f, 1.f, 1.f);
  const float t0 = (float)((idx * 4) & (TT - 1));  // TT=1024 divides 4-runs
  reinterpret_cast<float4*>(cov)[idx] =
      make_float4(t0, t0 + 1.f, t0 + 2.f, t0 + 3.f);
}

// ---- Fallback path (tiny ws): atomic accumulate + separate fill ----
__global__ __launch_bounds__(256) void sum_atomic_kernel(
    const float* __restrict__ values, float* __restrict__ ctx) {
  const int chunk = blockIdx.x;
  const int b = blockIdx.y;
  const int d4 = threadIdx.x;
  const float4* vp = reinterpret_cast<const float4*>(values) +
                     ((size_t)b * TT + (size_t)chunk * TSUB) * DD4 + d4;
  float4 acc = make_float4(0.f, 0.f, 0.f, 0.f);
#pragma unroll
  for (int t = 0; t < TSUB; ++t) {
    float4 v = vp[(size_t)t * DD4];
    acc.x += v.x;
    acc.y += v.y;
    acc.z += v.z;
    acc.w += v.w;
  }
  float* o = ctx + (size_t)b * DD + (size_t)d4 * 4;
  atomicAdd(o + 0, acc.x);
  atomicAdd(o + 1, acc.y);
  atomicAdd(o + 2, acc.z);
  atomicAdd(o + 3, acc.w);
}

__global__ __launch_bounds__(256) void fill_kernel(float* __restrict__ aw,
                                                   float* __restrict__ cov) {
  const int idx = blockIdx.x * 256 + threadIdx.x;
  aw[idx] = 1.0f;
  cov[idx] = (float)(idx & (TT - 1));
}

extern "C" void kernel_launch(void* const* d_in, const int* in_sizes, int n_in,
                              void* d_out, int out_size, void* d_ws,
                              size_t ws_size, hipStream_t stream) {
  // Inputs: 0=query, 1=values, 2=W1, 3=b1, 4=W2, 5=b2, 6=W3, 7=b3, 8=V, 9=bV.
  const float* values = (const float*)d_in[1];

  // Output: ctx [BB*DD] | attention_weights [BB*TT] | coverage [BB*TT]
  float* out = (float*)d_out;
  float* ctx = out;
  float* aw = out + (size_t)BB * DD;
  float* cov = aw + (size_t)BB * TT;

  const size_t need = (size_t)TCHUNKS * BB * DD * sizeof(float);
  if (ws_size >= need) {
    float* partial = (float*)d_ws;
    dim3 g1(TCHUNKS, BB);
    sum_partial_kernel<<<g1, 256, 0, stream>>>(values, partial);
    final_kernel<<<(BB * DD4) / 256, 256, 0, stream>>>(partial, ctx, aw, cov);
  } else {
    hipMemsetAsync(ctx, 0, (size_t)BB * DD * sizeof(float), stream);
    fill_kernel<<<(BB * TT) / 256, 256, 0, stream>>>(aw, cov);
    dim3 g1(TCHUNKS, BB);
    sum_atomic_kernel<<<g1, 256, 0, stream>>>(values, ctx);
  }
}